// Round 1
// baseline (1538.617 us; speedup 1.0000x reference)
//
#include <hip/hip_runtime.h>
#include <stdint.h>

typedef unsigned short u16;
typedef unsigned int   u32;

using f32x4 = __attribute__((ext_vector_type(4))) float;
using s16x8 = __attribute__((ext_vector_type(8))) short;

#define TT 20
#define BB 32
#define SS 400
#define DD 512
#define VV 50000
#define VP 50048   // 391*128

__device__ __forceinline__ float bf2f(u16 u){
  u32 x = ((u32)u) << 16;
  return __builtin_bit_cast(float, x);
}
__device__ __forceinline__ u16 f2bf(float f){
  u32 x = __builtin_bit_cast(u32, f);
  x = x + 0x7fffu + ((x >> 16) & 1u);
  return (u16)(x >> 16);
}
__device__ __forceinline__ float sigm(float x){ return 1.0f/(1.0f + __expf(-x)); }
__device__ __forceinline__ float tanh_fast(float x){
  float a = fabsf(x);
  if (a < 0.25f){ float x2 = x*x; return x + x*x2*(-0.33333334f + 0.13333334f*x2); }
  return tanhf(x);
}
__device__ __forceinline__ void gld16(const void* g, void* l){
  __builtin_amdgcn_global_load_lds((const __attribute__((address_space(1))) void*)g,
                                   (__attribute__((address_space(3))) void*)l, 16, 0, 0);
}

// ---------------- prep: transposes/casts of small weights + state init ----------------
__global__ __launch_bounds__(256) void k_prep(
    const float* __restrict__ W_proj, const float* __restrict__ enc_W,
    const float* __restrict__ dec_W,  const float* __restrict__ W_ih,
    const float* __restrict__ W_hh,   const float* __restrict__ b_ih,
    const float* __restrict__ b_hh,   const float* __restrict__ h0,
    const float* __restrict__ c0,
    u16* __restrict__ WpT, u16* __restrict__ encWT, u16* __restrict__ decWT,
    u16* __restrict__ Wihb, u16* __restrict__ Whhb, float* __restrict__ bg,
    u16* __restrict__ hb0, u16* __restrict__ hb1, float* __restrict__ c_st)
{
  int i = blockIdx.x*256 + threadIdx.x;
  if (i < 786432){ int j = i >> 9, k = i & 511; WpT[i] = f2bf(W_proj[k*1536 + j]); return; }
  i -= 786432;
  if (i < 262144){ int k = i >> 9, ii = i & 511; encWT[i] = f2bf(enc_W[ii*512 + k]); return; }
  i -= 262144;
  if (i < 262144){ int k = i >> 9, ii = i & 511; decWT[i] = f2bf(dec_W[ii*512 + k]); return; }
  i -= 262144;
  if (i < 1048576){ Wihb[i] = f2bf(W_ih[i]); return; }
  i -= 1048576;
  if (i < 1048576){ Whhb[i] = f2bf(W_hh[i]); return; }
  i -= 1048576;
  if (i < 2048){ bg[i] = b_ih[i] + b_hh[i]; return; }
  i -= 2048;
  if (i < 16384){ c_st[i] = c0[i]; hb0[i] = f2bf(h0[i]); hb1[i] = 0; return; }
}

// ---------------- cast W_emb -> bf16 with zero pad rows ----------------
__global__ __launch_bounds__(256) void k_cast_emb(const float* __restrict__ in, u16* __restrict__ out){
  int i = blockIdx.x*256 + threadIdx.x;
  int base = i*4;
  if (base >= VP*DD) return;
  uint2 o;
  if (base < VV*DD){
    float4 v = *(const float4*)&in[base];
    o.x = (u32)f2bf(v.x) | ((u32)f2bf(v.y) << 16);
    o.y = (u32)f2bf(v.z) | ((u32)f2bf(v.w) << 16);
  } else { o.x = 0u; o.y = 0u; }
  *(uint2*)&out[base] = o;
}

// ---------------- cast h_e -> bf16 ----------------
__global__ __launch_bounds__(256) void k_cast_he(const float* __restrict__ in, u16* __restrict__ out){
  int i = blockIdx.x*256 + threadIdx.x;
  int base = i*4;
  if (base >= SS*BB*DD) return;
  float4 v = *(const float4*)&in[base];
  uint2 o;
  o.x = (u32)f2bf(v.x) | ((u32)f2bf(v.y) << 16);
  o.y = (u32)f2bf(v.z) | ((u32)f2bf(v.w) << 16);
  *(uint2*)&out[base] = o;
}

// ---------------- gather embeddings for all (t,b) ----------------
__global__ __launch_bounds__(256) void k_gather(const int* __restrict__ inp,
                                                const u16* __restrict__ Wb, u16* __restrict__ out){
  int i = blockIdx.x*256 + threadIdx.x;
  if (i >= TT*BB*DD) return;
  int r = i >> 9, k = i & 511;
  out[i] = Wb[(size_t)inp[r]*DD + k];
}

// ---------------- bf16 GEMM: C[M,N] = A[M,K] @ B[N,K]^T, 128x128 tiles ----------------
// EPI: 0 = fp32 out, 1 = tanh->bf16, 2 = bf16, 3 = fp32 + bias with col<nmax guard
template<int EPI>
__global__ __launch_bounds__(256) void gemm_bt(
    const u16* __restrict__ A, const u16* __restrict__ B,
    float* __restrict__ Cf, u16* __restrict__ Cb, const float* __restrict__ bias,
    int K, int TM, int ldc, int nmax)
{
  __shared__ __align__(16) u16 As[128*32];
  __shared__ __align__(16) u16 Bs[128*32];
  const int bid = blockIdx.x;
  const int mt = bid % TM, nt = bid / TM;
  const int tid = threadIdx.x;
  const int w = tid >> 6, l = tid & 63;
  const int m0 = mt*128, n0 = nt*128;
  const int sgrow = l >> 2;          // row within 16-row chunk
  const int sgk = (l & 3) * 8;       // k offset (u16 units)
  const int wm = (w >> 1)*64, wn = (w & 1)*64;
  const int fr = l & 15, fk = (l >> 4)*8;
  f32x4 acc[4][4] = {};
  for (int k0 = 0; k0 < K; k0 += 32){
    #pragma unroll
    for (int i = 0; i < 2; ++i){
      const int ci = w + i*4;
      gld16(A + (size_t)(m0 + ci*16 + sgrow)*K + (k0 + sgk), &As[ci*512]);
      gld16(B + (size_t)(n0 + ci*16 + sgrow)*K + (k0 + sgk), &Bs[ci*512]);
    }
    __syncthreads();
    s16x8 af[4], bfr[4];
    #pragma unroll
    for (int i = 0; i < 4; ++i){
      af[i]  = *(const s16x8*)&As[(wm + i*16 + fr)*32 + fk];
      bfr[i] = *(const s16x8*)&Bs[(wn + i*16 + fr)*32 + fk];
    }
    #pragma unroll
    for (int i = 0; i < 4; ++i)
      #pragma unroll
      for (int j = 0; j < 4; ++j)
        acc[i][j] = __builtin_amdgcn_mfma_f32_16x16x32_bf16(af[i], bfr[j], acc[i][j], 0, 0, 0);
    __syncthreads();
  }
  #pragma unroll
  for (int i = 0; i < 4; ++i){
    #pragma unroll
    for (int j = 0; j < 4; ++j){
      #pragma unroll
      for (int r = 0; r < 4; ++r){
        const int row = m0 + wm + i*16 + (l >> 4)*4 + r;
        const int col = n0 + wn + j*16 + fr;
        const float v = acc[i][j][r];
        if constexpr (EPI == 0){ Cf[(size_t)row*ldc + col] = v; }
        else if constexpr (EPI == 1){ Cb[(size_t)row*ldc + col] = f2bf(tanh_fast(v)); }
        else if constexpr (EPI == 2){ Cb[(size_t)row*ldc + col] = f2bf(v); }
        else { if (col < nmax) Cf[(size_t)row*ldc + col] = v + bias[col]; }
      }
    }
  }
}

// ---------------- fused h@W_hh GEMM + LSTM cell ----------------
__global__ __launch_bounds__(256) void k_gatecell(
    const u16* __restrict__ hcur, const u16* __restrict__ Whh,
    const float* __restrict__ X, const float* __restrict__ bg,
    float* __restrict__ c_st, float* __restrict__ hist,
    float* __restrict__ ccat, u16* __restrict__ hnxt, int t)
{
  const int tid = threadIdx.x;
  const int w = blockIdx.x*4 + (tid >> 6);   // 0..31, d-slice
  const int l = tid & 63;
  const int d0 = w*16;
  const int fr = l & 15, fk = (l >> 4)*8;
  f32x4 acc[2][4] = {};
  for (int k0 = 0; k0 < 512; k0 += 32){
    s16x8 af[2], bfr[4];
    #pragma unroll
    for (int m = 0; m < 2; ++m)
      af[m] = *(const s16x8*)&hcur[(m*16 + fr)*512 + k0 + fk];
    #pragma unroll
    for (int g = 0; g < 4; ++g)
      bfr[g] = *(const s16x8*)&Whh[(size_t)(g*512 + d0 + fr)*512 + k0 + fk];
    #pragma unroll
    for (int m = 0; m < 2; ++m)
      #pragma unroll
      for (int g = 0; g < 4; ++g)
        acc[m][g] = __builtin_amdgcn_mfma_f32_16x16x32_bf16(af[m], bfr[g], acc[m][g], 0, 0, 0);
  }
  const int d = d0 + fr;
  #pragma unroll
  for (int m = 0; m < 2; ++m){
    #pragma unroll
    for (int r = 0; r < 4; ++r){
      const int b = m*16 + (l >> 4)*4 + r;
      const size_t xb = ((size_t)(t*BB + b))*2048;
      float iv = acc[m][0][r] + X[xb +    0 + d] + bg[   0 + d];
      float fv = acc[m][1][r] + X[xb +  512 + d] + bg[ 512 + d];
      float gv = acc[m][2][r] + X[xb + 1024 + d] + bg[1024 + d];
      float ov = acc[m][3][r] + X[xb + 1536 + d] + bg[1536 + d];
      float co = c_st[b*512 + d];
      float cn = sigm(fv)*co + sigm(iv)*tanhf(gv);
      float hd = sigm(ov)*tanhf(cn);
      c_st[b*512 + d] = cn;
      hist[((size_t)(t*BB + b))*512 + d] = hd;
      ccat[((size_t)(t*BB + b))*1536 + d] = hd;
      hnxt[b*512 + d] = f2bf(hd);
    }
  }
}

// ---------------- all per-step dot products: enc scores, gd_t, dec scores ----------------
__global__ __launch_bounds__(256) void k_scores(
    const u16* __restrict__ hcur, const u16* __restrict__ ge,
    const u16* __restrict__ decWT, u16* __restrict__ gd,
    float* __restrict__ se, float* __restrict__ sd, int t)
{
  const int G = blockIdx.x*16 + (threadIdx.x >> 4);
  const int li = threadIdx.x & 15;
  const int nEnc = SS*BB;           // 12800
  const int nGd = BB*DD;            // 16384
  const int tot = nEnc + nGd + BB*t;
  if (G >= tot) return;
  const u16 *pa, *pb;
  if (G < nEnc){
    int b = G & 31;
    pa = hcur + b*512; pb = ge + (size_t)G*512;
  } else if (G < nEnc + nGd){
    int G2 = G - nEnc; int b = G2 >> 9, k = G2 & 511;
    pa = hcur + b*512; pb = decWT + (size_t)k*512;
  } else {
    int G3 = G - nEnc - nGd; int u = G3 >> 5, b = G3 & 31;
    pa = hcur + b*512; pb = gd + ((size_t)(u*BB + b))*512;
  }
  float acc = 0.0f;
  const int kb = li*32;
  #pragma unroll
  for (int j = 0; j < 32; j += 8){
    s16x8 va = *(const s16x8*)&pa[kb + j];
    s16x8 vb = *(const s16x8*)&pb[kb + j];
    #pragma unroll
    for (int q = 0; q < 8; ++q) acc += bf2f((u16)va[q])*bf2f((u16)vb[q]);
  }
  acc += __shfl_xor(acc, 8); acc += __shfl_xor(acc, 4);
  acc += __shfl_xor(acc, 2); acc += __shfl_xor(acc, 1);
  if (li == 0){
    if (G < nEnc){ int s = G >> 5, b = G & 31; se[b*SS + s] = acc; }
    else if (G < nEnc + nGd){ int G2 = G - nEnc; int b = G2 >> 9, k = G2 & 511;
      gd[((size_t)(t*BB + b))*512 + k] = f2bf(acc); }
    else { int G3 = G - nEnc - nGd; int u = G3 >> 5, b = G3 & 31; sd[b*TT + u] = acc; }
  }
}

// ---------------- softmax + contexts + ccat assembly ----------------
__global__ __launch_bounds__(128) void k_ctx(
    const float* __restrict__ se, const float* __restrict__ sd,
    const u16* __restrict__ he, const float* __restrict__ hist,
    float* __restrict__ ccat, float* __restrict__ ae_all, int t)
{
  __shared__ float ael[SS];
  __shared__ float red[128];
  __shared__ float adl[TT];
  __shared__ float bc0;
  const int b = blockIdx.x >> 2, dc = blockIdx.x & 3;
  const int tid = threadIdx.x;
  // encoder softmax
  float lm = -1e30f;
  for (int s = tid; s < SS; s += 128) lm = fmaxf(lm, se[b*SS + s]);
  red[tid] = lm; __syncthreads();
  for (int st = 64; st; st >>= 1){ if (tid < st) red[tid] = fmaxf(red[tid], red[tid + st]); __syncthreads(); }
  const float M = red[0]; __syncthreads();
  float ls = 0.0f;
  for (int s = tid; s < SS; s += 128){ float p = __expf(se[b*SS + s] - M); ael[s] = p; ls += p; }
  red[tid] = ls; __syncthreads();
  for (int st = 64; st; st >>= 1){ if (tid < st) red[tid] += red[tid + st]; __syncthreads(); }
  const float inv = 1.0f/red[0];
  // decoder softmax (tiny)
  if (t > 0){
    if (tid < t) adl[tid] = sd[b*TT + tid];
    __syncthreads();
    if (tid == 0){
      float m2 = -1e30f;
      for (int u = 0; u < t; ++u) m2 = fmaxf(m2, adl[u]);
      float s2 = 0.0f;
      for (int u = 0; u < t; ++u){ float p = __expf(adl[u] - m2); adl[u] = p; s2 += p; }
      bc0 = 1.0f/s2;
    }
    __syncthreads();
  }
  const int d = dc*128 + tid;
  float ce = 0.0f;
  #pragma unroll 8
  for (int s = 0; s < SS; ++s) ce += ael[s]*bf2f(he[((size_t)(s*BB + b))*512 + d]);
  ce *= inv;
  float cd = 0.0f;
  if (t > 0){
    for (int u = 0; u < t; ++u) cd += adl[u]*hist[((size_t)(u*BB + b))*512 + d];
    cd *= bc0;
  }
  const size_t cro = ((size_t)(t*BB + b))*1536;
  ccat[cro +  512 + d] = ce;
  ccat[cro + 1024 + d] = cd;
  if (dc == 0){
    for (int s = tid; s < SS; s += 128) ae_all[((size_t)(t*BB + b))*SS + s] = ael[s]*inv;
  }
}

// ---------------- p_switch + ccat cast ----------------
__global__ __launch_bounds__(256) void k_pswitch(
    const float* __restrict__ ccat, const float* __restrict__ puW,
    const float* __restrict__ puB, u16* __restrict__ ccatb, float* __restrict__ ps)
{
  const int r = blockIdx.x, tid = threadIdx.x;
  __shared__ float red[256];
  float s = 0.0f;
  for (int k = tid; k < 1536; k += 256){
    float v = ccat[(size_t)r*1536 + k];
    ccatb[(size_t)r*1536 + k] = f2bf(v);
    s += v*puW[k];
  }
  red[tid] = s; __syncthreads();
  for (int st = 128; st; st >>= 1){ if (tid < st) red[tid] += red[tid + st]; __syncthreads(); }
  if (tid == 0) ps[r] = 1.0f/(1.0f + __expf(-(red[0] + puB[0])));
}

// ---------------- vocab softmax (in-place in d_out) + (1-ps) scale ----------------
__global__ __launch_bounds__(256) void k_softmax(float* __restrict__ out, const float* __restrict__ ps)
{
  const int r = blockIdx.x, tid = threadIdx.x;
  __shared__ float rm[256], rs[256];
  float m = -1e30f, s = 0.0f;
  float* row = out + (size_t)r*VV;
  for (int v = tid; v < VV; v += 256){
    if (v == 1) continue;
    float x = row[v];
    if (x > m){ s = s*__expf(m - x) + 1.0f; m = x; }
    else s += __expf(x - m);
  }
  rm[tid] = m; rs[tid] = s; __syncthreads();
  for (int st = 128; st; st >>= 1){
    if (tid < st){
      float m2 = fmaxf(rm[tid], rm[tid + st]);
      rs[tid] = rs[tid]*__expf(rm[tid] - m2) + rs[tid + st]*__expf(rm[tid + st] - m2);
      rm[tid] = m2;
    }
    __syncthreads();
  }
  const float M = rm[0];
  const float inv = (1.0f - ps[r])/rs[0];
  for (int v = tid; v < VV; v += 256)
    row[v] = (v == 1) ? 0.0f : __expf(row[v] - M)*inv;
}

// ---------------- copy-distribution scatter ----------------
__global__ __launch_bounds__(256) void k_scatter(
    float* __restrict__ out, const int* __restrict__ src,
    const float* __restrict__ ae_all, const float* __restrict__ ps)
{
  const int idx = blockIdx.x*256 + threadIdx.x;
  if (idx >= TT*BB*SS) return;
  const int s = idx % SS;
  const int rb = idx / SS;          // t*32+b
  const int b = rb & 31;
  const int v = src[s*BB + b];
  atomicAdd(&out[(size_t)rb*VV + v], ae_all[(size_t)rb*SS + s]*ps[rb]);
}

extern "C" void kernel_launch(void* const* d_in, const int* in_sizes, int n_in,
                              void* d_out, int out_size, void* d_ws, size_t ws_size,
                              hipStream_t stream)
{
  const int*   inputs = (const int*)  d_in[0];
  const int*   src    = (const int*)  d_in[1];
  const float* h_e    = (const float*)d_in[2];
  const float* h0     = (const float*)d_in[3];
  const float* c0     = (const float*)d_in[4];
  const float* W_emb  = (const float*)d_in[5];
  const float* W_proj = (const float*)d_in[6];
  const float* b_out  = (const float*)d_in[7];
  const float* puW    = (const float*)d_in[8];
  const float* puB    = (const float*)d_in[9];
  const float* enc_W  = (const float*)d_in[10];
  const float* dec_W  = (const float*)d_in[11];
  const float* W_ih   = (const float*)d_in[12];
  const float* W_hh   = (const float*)d_in[13];
  const float* b_ih   = (const float*)d_in[14];
  const float* b_hh   = (const float*)d_in[15];
  float* out = (float*)d_out;

  char* wp = (char*)d_ws;
  auto alloc = [&](size_t bytes) -> char* {
    char* p = wp; wp += (bytes + 255) & ~(size_t)255; return p;
  };
  u16*   Wembb = (u16*)  alloc((size_t)VP*DD*2);
  u16*   Woutb = (u16*)  alloc((size_t)VP*1536*2);
  u16*   WpT   = (u16*)  alloc(1536*512*2);
  u16*   encWT = (u16*)  alloc(512*512*2);
  u16*   decWT = (u16*)  alloc(512*512*2);
  u16*   Wihb  = (u16*)  alloc(2048*512*2);
  u16*   Whhb  = (u16*)  alloc(2048*512*2);
  float* bg    = (float*)alloc(2048*4);
  u16*   heb   = (u16*)  alloc((size_t)SS*BB*DD*2);
  u16*   ge    = (u16*)  alloc((size_t)SS*BB*DD*2);
  u16*   emba  = (u16*)  alloc((size_t)TT*BB*DD*2);
  float* X     = (float*)alloc((size_t)TT*BB*2048*4);
  u16*   hb0   = (u16*)  alloc(BB*DD*2);
  u16*   hb1   = (u16*)  alloc(BB*DD*2);
  float* c_st  = (float*)alloc(BB*DD*4);
  float* hist  = (float*)alloc((size_t)TT*BB*DD*4);
  u16*   gd    = (u16*)  alloc((size_t)TT*BB*DD*2);
  float* ccat  = (float*)alloc((size_t)TT*BB*1536*4);
  u16*   ccatb = (u16*)  alloc((size_t)TT*BB*1536*2);
  float* se    = (float*)alloc(BB*SS*4);
  float* sdb   = (float*)alloc(BB*TT*4);
  float* aeall = (float*)alloc((size_t)TT*BB*SS*4);
  float* ps    = (float*)alloc(TT*BB*4);

  // prep / casts / gathers
  k_prep<<<13384, 256, 0, stream>>>(W_proj, enc_W, dec_W, W_ih, W_hh, b_ih, b_hh, h0, c0,
                                    WpT, encWT, decWT, Wihb, Whhb, bg, hb0, hb1, c_st);
  k_cast_emb<<<(VP*DD/4)/256, 256, 0, stream>>>(W_emb, Wembb);
  k_cast_he<<<(SS*BB*DD/4)/256, 256, 0, stream>>>(h_e, heb);
  k_gather<<<(TT*BB*DD + 255)/256, 256, 0, stream>>>(inputs, Wembb, emba);

  // big precomputes
  gemm_bt<1><<<391*12, 256, 0, stream>>>(Wembb, WpT, nullptr, Woutb, nullptr, 512, 391, 1536, 0);
  gemm_bt<0><<<5*16,   256, 0, stream>>>(emba, Wihb, X, nullptr, nullptr, 512, 5, 2048, 0);
  gemm_bt<2><<<100*4,  256, 0, stream>>>(heb, encWT, nullptr, ge, nullptr, 512, 100, 512, 0);

  // sequential scan
  for (int t = 0; t < TT; ++t){
    const u16* hcur = (t & 1) ? hb1 : hb0;
    u16*       hnxt = (t & 1) ? hb0 : hb1;
    k_gatecell<<<8, 256, 0, stream>>>(hcur, Whhb, X, bg, c_st, hist, ccat, hnxt, t);
    const int nDots = SS*BB + BB*DD + BB*t;
    k_scores<<<(nDots + 15)/16, 256, 0, stream>>>(hnxt, ge, decWT, gd, se, sdb, t);
    k_ctx<<<128, 128, 0, stream>>>(se, sdb, heb, hist, ccat, aeall, t);
  }

  // pointer-generator tail
  k_pswitch<<<TT*BB, 256, 0, stream>>>(ccat, puW, puB, ccatb, ps);
  gemm_bt<3><<<5*391, 256, 0, stream>>>(ccatb, Woutb, out, nullptr, b_out, 1536, 5, VV, VV);
  k_softmax<<<TT*BB, 256, 0, stream>>>(out, ps);
  k_scatter<<<(TT*BB*SS + 255)/256, 256, 0, stream>>>(out, src, aeall, ps);
}

// Round 2
// 1145.352 us; speedup vs baseline: 1.3434x; 1.3434x over previous
//
#include <hip/hip_runtime.h>
#include <stdint.h>

typedef unsigned short u16;
typedef unsigned int   u32;

using f32x4 = __attribute__((ext_vector_type(4))) float;
using s16x8 = __attribute__((ext_vector_type(8))) short;

#define TT 20
#define BB 32
#define SS 400
#define DD 512
#define VV 50000
#define VP 50048   // 391*128

__device__ __forceinline__ float bf2f(u16 u){
  u32 x = ((u32)u) << 16;
  return __builtin_bit_cast(float, x);
}
__device__ __forceinline__ u16 f2bf(float f){
  u32 x = __builtin_bit_cast(u32, f);
  x = x + 0x7fffu + ((x >> 16) & 1u);
  return (u16)(x >> 16);
}
__device__ __forceinline__ float sigm(float x){ return 1.0f/(1.0f + __expf(-x)); }
__device__ __forceinline__ float tanh_fast(float x){
  float a = fabsf(x);
  if (a < 0.25f){ float x2 = x*x; return x + x*x2*(-0.33333334f + 0.13333334f*x2); }
  return tanhf(x);
}
__device__ __forceinline__ void gld16(const void* g, void* l){
  __builtin_amdgcn_global_load_lds((const __attribute__((address_space(1))) void*)g,
                                   (__attribute__((address_space(3))) void*)l, 16, 0, 0);
}

// ---------------- prep: transposes/casts of small weights + state init ----------------
__global__ __launch_bounds__(256) void k_prep(
    const float* __restrict__ W_proj, const float* __restrict__ enc_W,
    const float* __restrict__ dec_W,  const float* __restrict__ W_ih,
    const float* __restrict__ W_hh,   const float* __restrict__ b_ih,
    const float* __restrict__ b_hh,   const float* __restrict__ h0,
    const float* __restrict__ c0,
    u16* __restrict__ WpT, u16* __restrict__ encWT, u16* __restrict__ decWT,
    u16* __restrict__ Wihb, u16* __restrict__ Whhb, float* __restrict__ bg,
    u16* __restrict__ hb0, u16* __restrict__ hb1, float* __restrict__ c_st,
    float* __restrict__ psacc)
{
  int i = blockIdx.x*256 + threadIdx.x;
  if (i < 786432){ int j = i >> 9, k = i & 511; WpT[i] = f2bf(W_proj[k*1536 + j]); return; }
  i -= 786432;
  if (i < 262144){ int k = i >> 9, ii = i & 511; encWT[i] = f2bf(enc_W[ii*512 + k]); return; }
  i -= 262144;
  if (i < 262144){ int k = i >> 9, ii = i & 511; decWT[i] = f2bf(dec_W[ii*512 + k]); return; }
  i -= 262144;
  if (i < 1048576){ Wihb[i] = f2bf(W_ih[i]); return; }
  i -= 1048576;
  if (i < 1048576){ Whhb[i] = f2bf(W_hh[i]); return; }
  i -= 1048576;
  if (i < 2048){ bg[i] = b_ih[i] + b_hh[i]; return; }
  i -= 2048;
  if (i < 16384){ c_st[i] = c0[i]; hb0[i] = f2bf(h0[i]); hb1[i] = 0; return; }
  i -= 16384;
  if (i < TT*BB){ psacc[i] = 0.0f; return; }
}

// ---------------- cast W_emb -> bf16 with zero pad rows ----------------
__global__ __launch_bounds__(256) void k_cast_emb(const float* __restrict__ in, u16* __restrict__ out){
  int i = blockIdx.x*256 + threadIdx.x;
  int base = i*4;
  if (base >= VP*DD) return;
  uint2 o;
  if (base < VV*DD){
    float4 v = *(const float4*)&in[base];
    o.x = (u32)f2bf(v.x) | ((u32)f2bf(v.y) << 16);
    o.y = (u32)f2bf(v.z) | ((u32)f2bf(v.w) << 16);
  } else { o.x = 0u; o.y = 0u; }
  *(uint2*)&out[base] = o;
}

// ---------------- cast h_e -> bf16 ----------------
__global__ __launch_bounds__(256) void k_cast_he(const float* __restrict__ in, u16* __restrict__ out){
  int i = blockIdx.x*256 + threadIdx.x;
  int base = i*4;
  if (base >= SS*BB*DD) return;
  float4 v = *(const float4*)&in[base];
  uint2 o;
  o.x = (u32)f2bf(v.x) | ((u32)f2bf(v.y) << 16);
  o.y = (u32)f2bf(v.z) | ((u32)f2bf(v.w) << 16);
  *(uint2*)&out[base] = o;
}

// ---------------- gather embeddings for all (t,b) ----------------
__global__ __launch_bounds__(256) void k_gather(const int* __restrict__ inp,
                                                const u16* __restrict__ Wb, u16* __restrict__ out){
  int i = blockIdx.x*256 + threadIdx.x;
  if (i >= TT*BB*DD) return;
  int r = i >> 9, k = i & 511;
  out[i] = Wb[(size_t)inp[r]*DD + k];
}

// ---------------- bf16 GEMM: C[M,N] = A[M,K] @ B[N,K]^T, 128x128 tiles ----------------
// EPI: 0 = fp32 out, 1 = tanh->bf16, 2 = bf16, 3 = bf16 + bias with col<nmax guard
// ORD: 0 = plain mt-fastest, 1 = XCD-chunk + nt-fastest, 2 = XCD-chunk + mt-fastest
template<int EPI, int ORD>
__global__ __launch_bounds__(256) void gemm_bt(
    const u16* __restrict__ A, const u16* __restrict__ B,
    float* __restrict__ Cf, u16* __restrict__ Cb, const float* __restrict__ bias,
    int K, int TM, int TN, int ldc, int nmax)
{
  __shared__ __align__(16) u16 As[128*32];
  __shared__ __align__(16) u16 Bs[128*32];
  int bid = blockIdx.x;
  if (ORD >= 1){
    const int n = TM*TN, x = bid & 7, i = bid >> 3;
    const int q = n >> 3, r = n & 7;
    bid = (x < r ? x*(q+1) : r*(q+1) + (x-r)*q) + i;
  }
  const int mt = (ORD == 1) ? bid / TN : bid % TM;
  const int nt = (ORD == 1) ? bid % TN : bid / TM;
  const int tid = threadIdx.x;
  const int w = tid >> 6, l = tid & 63;
  const int m0 = mt*128, n0 = nt*128;
  const int sgrow = l >> 2;                            // row within 16-row chunk
  const int sgk = (((l & 3) ^ ((l >> 3) & 3))) * 8;    // swizzled global k-offset
  const int wm = (w >> 1)*64, wn = (w & 1)*64;
  const int fr = l & 15;
  const int fk = (((l >> 4) ^ ((l >> 1) & 3))) * 8;    // swizzled LDS read slot
  f32x4 acc[4][4] = {};
  for (int k0 = 0; k0 < K; k0 += 32){
    #pragma unroll
    for (int i = 0; i < 2; ++i){
      const int ci = w + i*4;
      gld16(A + (size_t)(m0 + ci*16 + sgrow)*K + (k0 + sgk), &As[ci*512]);
      gld16(B + (size_t)(n0 + ci*16 + sgrow)*K + (k0 + sgk), &Bs[ci*512]);
    }
    __syncthreads();
    s16x8 af[4], bfr[4];
    #pragma unroll
    for (int i = 0; i < 4; ++i){
      af[i]  = *(const s16x8*)&As[(wm + i*16 + fr)*32 + fk];
      bfr[i] = *(const s16x8*)&Bs[(wn + i*16 + fr)*32 + fk];
    }
    #pragma unroll
    for (int i = 0; i < 4; ++i)
      #pragma unroll
      for (int j = 0; j < 4; ++j)
        acc[i][j] = __builtin_amdgcn_mfma_f32_16x16x32_bf16(af[i], bfr[j], acc[i][j], 0, 0, 0);
    __syncthreads();
  }
  #pragma unroll
  for (int i = 0; i < 4; ++i){
    #pragma unroll
    for (int j = 0; j < 4; ++j){
      #pragma unroll
      for (int r = 0; r < 4; ++r){
        const int row = m0 + wm + i*16 + (l >> 4)*4 + r;
        const int col = n0 + wn + j*16 + fr;
        const float v = acc[i][j][r];
        if constexpr (EPI == 0){ Cf[(size_t)row*ldc + col] = v; }
        else if constexpr (EPI == 1){ Cb[(size_t)row*ldc + col] = f2bf(tanh_fast(v)); }
        else if constexpr (EPI == 2){ Cb[(size_t)row*ldc + col] = f2bf(v); }
        else { if (col < nmax) Cb[(size_t)row*ldc + col] = f2bf(v + bias[col]); }
      }
    }
  }
}

// ---------------- fused h@W_hh GEMM + LSTM cell, plus gd_{t-1} projection ----------------
__global__ __launch_bounds__(256) void k_gatecell(
    const u16* __restrict__ hcur, const u16* __restrict__ Whh,
    const u16* __restrict__ decWT,
    const float* __restrict__ X, const float* __restrict__ bg,
    float* __restrict__ c_st, float* __restrict__ hist,
    u16* __restrict__ hnxt, u16* __restrict__ gd, int t)
{
  const int tid = threadIdx.x;
  const int bi = blockIdx.x;
  const int l = tid & 63;
  const int fr = l & 15, fk = (l >> 4)*8;
  if (bi < 8){
    const int w = bi*4 + (tid >> 6);   // 0..31, d-slice
    const int d0 = w*16;
    f32x4 acc[2][4] = {};
    for (int k0 = 0; k0 < 512; k0 += 32){
      s16x8 af[2], bfr[4];
      #pragma unroll
      for (int m = 0; m < 2; ++m)
        af[m] = *(const s16x8*)&hcur[(m*16 + fr)*512 + k0 + fk];
      #pragma unroll
      for (int g = 0; g < 4; ++g)
        bfr[g] = *(const s16x8*)&Whh[(size_t)(g*512 + d0 + fr)*512 + k0 + fk];
      #pragma unroll
      for (int m = 0; m < 2; ++m)
        #pragma unroll
        for (int g = 0; g < 4; ++g)
          acc[m][g] = __builtin_amdgcn_mfma_f32_16x16x32_bf16(af[m], bfr[g], acc[m][g], 0, 0, 0);
    }
    const int d = d0 + fr;
    #pragma unroll
    for (int m = 0; m < 2; ++m){
      #pragma unroll
      for (int r = 0; r < 4; ++r){
        const int b = m*16 + (l >> 4)*4 + r;
        const size_t xb = ((size_t)(t*BB + b))*2048;
        float iv = acc[m][0][r] + X[xb +    0 + d] + bg[   0 + d];
        float fv = acc[m][1][r] + X[xb +  512 + d] + bg[ 512 + d];
        float gv = acc[m][2][r] + X[xb + 1024 + d] + bg[1024 + d];
        float ov = acc[m][3][r] + X[xb + 1536 + d] + bg[1536 + d];
        float co = c_st[b*512 + d];
        float cn = sigm(fv)*co + sigm(iv)*tanhf(gv);
        float hd = sigm(ov)*tanhf(cn);
        c_st[b*512 + d] = cn;
        hist[((size_t)(t*BB + b))*512 + d] = hd;
        hnxt[b*512 + d] = f2bf(hd);
      }
    }
  } else {
    // gd_{t-1} = h_{t-1} @ dec_W  (hcur holds hd_{t-1} = bf16 of last step's output)
    if (t == 0) return;
    const int w2 = (bi - 8)*4 + (tid >> 6);  // 0..31
    const int k0s = w2*16;
    f32x4 acc[2] = {};
    for (int k0 = 0; k0 < 512; k0 += 32){
      s16x8 af[2];
      #pragma unroll
      for (int m = 0; m < 2; ++m)
        af[m] = *(const s16x8*)&hcur[(m*16 + fr)*512 + k0 + fk];
      s16x8 bfr = *(const s16x8*)&decWT[(size_t)(k0s + fr)*512 + k0 + fk];
      #pragma unroll
      for (int m = 0; m < 2; ++m)
        acc[m] = __builtin_amdgcn_mfma_f32_16x16x32_bf16(af[m], bfr, acc[m], 0, 0, 0);
    }
    #pragma unroll
    for (int m = 0; m < 2; ++m){
      #pragma unroll
      for (int r = 0; r < 4; ++r){
        const int b = m*16 + (l >> 4)*4 + r;
        gd[((size_t)((t-1)*BB + b))*512 + k0s + fr] = f2bf(acc[m][r]);
      }
    }
  }
}

// ---------------- per-step dot products: enc scores + dec scores ----------------
__global__ __launch_bounds__(256) void k_scores(
    const u16* __restrict__ hcur, const u16* __restrict__ ge,
    const u16* __restrict__ gd,
    float* __restrict__ se, float* __restrict__ sd, int t)
{
  const int G = blockIdx.x*16 + (threadIdx.x >> 4);
  const int li = threadIdx.x & 15;
  const int nEnc = SS*BB;           // 12800
  const int tot = nEnc + BB*t;
  if (G >= tot) return;
  const u16 *pa, *pb;
  int b;
  if (G < nEnc){
    b = G & 31;
    pb = ge + (size_t)G*512;
  } else {
    int G3 = G - nEnc; int u = G3 >> 5; b = G3 & 31;
    pb = gd + ((size_t)(u*BB + b))*512;
  }
  pa = hcur + b*512;
  float acc = 0.0f;
  #pragma unroll
  for (int jj = 0; jj < 4; ++jj){
    const int off = li*8 + jj*128;
    s16x8 va = *(const s16x8*)&pa[off];
    s16x8 vb = *(const s16x8*)&pb[off];
    #pragma unroll
    for (int q = 0; q < 8; ++q) acc += bf2f((u16)va[q])*bf2f((u16)vb[q]);
  }
  acc += __shfl_xor(acc, 8); acc += __shfl_xor(acc, 4);
  acc += __shfl_xor(acc, 2); acc += __shfl_xor(acc, 1);
  if (li == 0){
    if (G < nEnc){ int s = G >> 5; se[b*SS + s] = acc; }
    else { int G3 = G - nEnc; int u = G3 >> 5; sd[b*TT + u] = acc; }
  }
}

// ---------------- softmax + contexts + ccat(bf16) + p_switch partial ----------------
__global__ __launch_bounds__(256) void k_ctx(
    const float* __restrict__ se, const float* __restrict__ sd,
    const u16* __restrict__ he, const float* __restrict__ hist,
    const u16* __restrict__ hnxt, const float* __restrict__ puW,
    u16* __restrict__ ccatb, float* __restrict__ ae_all,
    float* __restrict__ psacc, int t)
{
  __shared__ float ael[SS];
  __shared__ float red[256];
  __shared__ float adl[TT];
  __shared__ float part[8*128];
  __shared__ float bc0s;
  const int b = blockIdx.x >> 2, dc = blockIdx.x & 3;
  const int tid = threadIdx.x;
  // encoder softmax (duplicated per dc-block, cheap)
  float lm = -1e30f;
  for (int s = tid; s < SS; s += 256) lm = fmaxf(lm, se[b*SS + s]);
  red[tid] = lm; __syncthreads();
  for (int st = 128; st; st >>= 1){ if (tid < st) red[tid] = fmaxf(red[tid], red[tid + st]); __syncthreads(); }
  const float M = red[0]; __syncthreads();
  float ls = 0.0f;
  for (int s = tid; s < SS; s += 256){ float p = __expf(se[b*SS + s] - M); ael[s] = p; ls += p; }
  red[tid] = ls; __syncthreads();
  for (int st = 128; st; st >>= 1){ if (tid < st) red[tid] += red[tid + st]; __syncthreads(); }
  const float inv = 1.0f/red[0];
  __syncthreads();
  // decoder softmax (tiny)
  if (t > 0){
    if (tid == 0){
      float m2 = -1e30f;
      for (int u = 0; u < t; ++u) m2 = fmaxf(m2, sd[b*TT + u]);
      float s2 = 0.0f;
      for (int u = 0; u < t; ++u){ float p = __expf(sd[b*TT + u] - m2); adl[u] = p; s2 += p; }
      bc0s = 1.0f/s2;
    }
    __syncthreads();
  }
  // ce: 8 s-groups x 32 threads x 4 d's
  const int g = tid >> 5, th = tid & 31;
  const int d0 = dc*128 + th*4;
  float c0 = 0, c1 = 0, c2 = 0, c3 = 0;
  for (int s = g; s < SS; s += 8){
    const float a = ael[s];
    uint2 hv = *(const uint2*)&he[((size_t)(s*BB + b))*512 + d0];
    c0 += a*bf2f((u16)(hv.x & 0xffff));
    c1 += a*bf2f((u16)(hv.x >> 16));
    c2 += a*bf2f((u16)(hv.y & 0xffff));
    c3 += a*bf2f((u16)(hv.y >> 16));
  }
  ((float4*)part)[g*32 + th] = float4{c0, c1, c2, c3};
  __syncthreads();
  float ce = 0.0f;
  if (tid < 128){
    #pragma unroll
    for (int g2 = 0; g2 < 8; ++g2) ce += part[g2*128 + tid];
    ce *= inv;
  }
  __syncthreads();
  // cd
  float e0 = 0, e1 = 0, e2 = 0, e3 = 0;
  for (int u = g; u < t; u += 8){
    const float a = adl[u];
    float4 hv = *(const float4*)&hist[((size_t)(u*BB + b))*512 + d0];
    e0 += a*hv.x; e1 += a*hv.y; e2 += a*hv.z; e3 += a*hv.w;
  }
  ((float4*)part)[g*32 + th] = float4{e0, e1, e2, e3};
  __syncthreads();
  float cd = 0.0f;
  if (tid < 128 && t > 0){
    #pragma unroll
    for (int g2 = 0; g2 < 8; ++g2) cd += part[g2*128 + tid];
    cd *= bc0s;
  }
  // writes + p_switch partial
  const int row = t*BB + b;
  float pv = 0.0f;
  if (tid < 128){
    const int dcol = dc*128 + tid;
    const size_t cro = (size_t)row*1536;
    u16 hv = hnxt[b*512 + dcol];
    ccatb[cro + dcol] = hv;
    ccatb[cro + 512 + dcol] = f2bf(ce);
    ccatb[cro + 1024 + dcol] = f2bf(cd);
    pv = bf2f(hv)*puW[dcol] + ce*puW[512 + dcol] + cd*puW[1024 + dcol];
  }
  red[tid] = pv; __syncthreads();
  for (int st = 128; st; st >>= 1){ if (tid < st) red[tid] += red[tid + st]; __syncthreads(); }
  if (tid == 0) atomicAdd(&psacc[row], red[0]);
  if (dc == 0){
    for (int s = tid; s < SS; s += 256) ae_all[(size_t)row*SS + s] = ael[s]*inv;
  }
}

// ---------------- finalize p_switch ----------------
__global__ __launch_bounds__(256) void k_finps(float* __restrict__ psacc, const float* __restrict__ puB){
  int i = blockIdx.x*256 + threadIdx.x;
  if (i < TT*BB) psacc[i] = 1.0f/(1.0f + __expf(-(psacc[i] + puB[0])));
}

// ---------------- vocab softmax from bf16 logits -> fp32 d_out, scaled by (1-ps) ----------------
__global__ __launch_bounds__(256) void k_softmax(
    const u16* __restrict__ lg, float* __restrict__ out, const float* __restrict__ ps)
{
  const int r = blockIdx.x, tid = threadIdx.x;
  __shared__ float rm[256], rs[256];
  const u16* row = lg + (size_t)r*VP;
  float m = -1e30f, s = 0.0f;
  for (int v8 = tid*8; v8 < VV; v8 += 2048){
    uint4 pk = *(const uint4*)&row[v8];
    u32 wds[4] = {pk.x, pk.y, pk.z, pk.w};
    #pragma unroll
    for (int q = 0; q < 8; ++q){
      if (v8 + q == 1) continue;
      float x = bf2f((u16)((wds[q >> 1] >> ((q & 1)*16)) & 0xffffu));
      if (x > m){ s = s*__expf(m - x) + 1.0f; m = x; }
      else s += __expf(x - m);
    }
  }
  rm[tid] = m; rs[tid] = s; __syncthreads();
  for (int st = 128; st; st >>= 1){
    if (tid < st){
      float m2 = fmaxf(rm[tid], rm[tid + st]);
      rs[tid] = rs[tid]*__expf(rm[tid] - m2) + rs[tid + st]*__expf(rm[tid + st] - m2);
      rm[tid] = m2;
    }
    __syncthreads();
  }
  const float M = rm[0];
  const float inv = (1.0f - ps[r])/rs[0];
  float* orow = out + (size_t)r*VV;
  for (int v8 = tid*8; v8 < VV; v8 += 2048){
    uint4 pk = *(const uint4*)&row[v8];
    u32 wds[4] = {pk.x, pk.y, pk.z, pk.w};
    float o[8];
    #pragma unroll
    for (int q = 0; q < 8; ++q){
      float x = bf2f((u16)((wds[q >> 1] >> ((q & 1)*16)) & 0xffffu));
      o[q] = (v8 + q == 1) ? 0.0f : __expf(x - M)*inv;
    }
    *(float4*)&orow[v8]     = float4{o[0], o[1], o[2], o[3]};
    *(float4*)&orow[v8 + 4] = float4{o[4], o[5], o[6], o[7]};
  }
}

// ---------------- copy-distribution scatter ----------------
__global__ __launch_bounds__(256) void k_scatter(
    float* __restrict__ out, const int* __restrict__ src,
    const float* __restrict__ ae_all, const float* __restrict__ ps)
{
  const int idx = blockIdx.x*256 + threadIdx.x;
  if (idx >= TT*BB*SS) return;
  const int s = idx % SS;
  const int rb = idx / SS;          // t*32+b
  const int b = rb & 31;
  const int v = src[s*BB + b];
  atomicAdd(&out[(size_t)rb*VV + v], ae_all[(size_t)rb*SS + s]*ps[rb]);
}

extern "C" void kernel_launch(void* const* d_in, const int* in_sizes, int n_in,
                              void* d_out, int out_size, void* d_ws, size_t ws_size,
                              hipStream_t stream)
{
  const int*   inputs = (const int*)  d_in[0];
  const int*   src    = (const int*)  d_in[1];
  const float* h_e    = (const float*)d_in[2];
  const float* h0     = (const float*)d_in[3];
  const float* c0     = (const float*)d_in[4];
  const float* W_emb  = (const float*)d_in[5];
  const float* W_proj = (const float*)d_in[6];
  const float* b_out  = (const float*)d_in[7];
  const float* puW    = (const float*)d_in[8];
  const float* puB    = (const float*)d_in[9];
  const float* enc_W  = (const float*)d_in[10];
  const float* dec_W  = (const float*)d_in[11];
  const float* W_ih   = (const float*)d_in[12];
  const float* W_hh   = (const float*)d_in[13];
  const float* b_ih   = (const float*)d_in[14];
  const float* b_hh   = (const float*)d_in[15];
  float* out = (float*)d_out;

  char* wp = (char*)d_ws;
  auto alloc = [&](size_t bytes) -> char* {
    char* p = wp; wp += (bytes + 255) & ~(size_t)255; return p;
  };
  // Early-dead region (reclaimed for bf16 logits after the scan):
  u16*   Wembb = (u16*)  alloc((size_t)VP*DD*2);      // dead after W_out GEMM
  u16*   WpT   = (u16*)  alloc(1536*512*2);           // dead after W_out GEMM
  u16*   encWT = (u16*)  alloc(512*512*2);            // dead after ge GEMM
  u16*   ge    = (u16*)  alloc((size_t)SS*BB*DD*2);   // dead after step-19 scores
  u16*   logitsb = (u16*)Wembb;                       // 640*VP*2 = 64.1MB <= 66.3MB above
  // Long-lived:
  u16*   Woutb = (u16*)  alloc((size_t)VP*1536*2);
  u16*   decWT = (u16*)  alloc(512*512*2);
  u16*   Wihb  = (u16*)  alloc(2048*512*2);
  u16*   Whhb  = (u16*)  alloc(2048*512*2);
  float* bg    = (float*)alloc(2048*4);
  u16*   heb   = (u16*)  alloc((size_t)SS*BB*DD*2);
  u16*   emba  = (u16*)  alloc((size_t)TT*BB*DD*2);
  float* X     = (float*)alloc((size_t)TT*BB*2048*4);
  u16*   hb0   = (u16*)  alloc(BB*DD*2);
  u16*   hb1   = (u16*)  alloc(BB*DD*2);
  float* c_st  = (float*)alloc(BB*DD*4);
  float* hist  = (float*)alloc((size_t)TT*BB*DD*4);
  u16*   gd    = (u16*)  alloc((size_t)TT*BB*DD*2);
  u16*   ccatb = (u16*)  alloc((size_t)TT*BB*1536*2);
  float* se    = (float*)alloc(BB*SS*4);
  float* sdb   = (float*)alloc(BB*TT*4);
  float* aeall = (float*)alloc((size_t)TT*BB*SS*4);
  float* psacc = (float*)alloc(TT*BB*4);

  // prep / casts / gathers
  k_prep<<<13387, 256, 0, stream>>>(W_proj, enc_W, dec_W, W_ih, W_hh, b_ih, b_hh, h0, c0,
                                    WpT, encWT, decWT, Wihb, Whhb, bg, hb0, hb1, c_st, psacc);
  k_cast_emb<<<(VP*DD/4)/256, 256, 0, stream>>>(W_emb, Wembb);
  k_cast_he<<<(SS*BB*DD/4)/256, 256, 0, stream>>>(h_e, heb);
  k_gather<<<(TT*BB*DD + 255)/256, 256, 0, stream>>>(inputs, Wembb, emba);

  // big precomputes
  gemm_bt<1,1><<<391*12, 256, 0, stream>>>(Wembb, WpT, nullptr, Woutb, nullptr, 512, 391, 12, 1536, 0);
  gemm_bt<0,0><<<5*16,   256, 0, stream>>>(emba, Wihb, X, nullptr, nullptr, 512, 5, 16, 2048, 0);
  gemm_bt<2,0><<<100*4,  256, 0, stream>>>(heb, encWT, nullptr, ge, nullptr, 512, 100, 4, 512, 0);

  // sequential scan
  for (int t = 0; t < TT; ++t){
    const u16* hcur = (t & 1) ? hb1 : hb0;
    u16*       hnxt = (t & 1) ? hb0 : hb1;
    k_gatecell<<<16, 256, 0, stream>>>(hcur, Whhb, decWT, X, bg, c_st, hist, hnxt, gd, t);
    const int nDots = SS*BB + BB*t;
    k_scores<<<(nDots + 15)/16, 256, 0, stream>>>(hnxt, ge, gd, se, sdb, t);
    k_ctx<<<128, 256, 0, stream>>>(se, sdb, heb, hist, hnxt, puW, ccatb, aeall, psacc, t);
  }

  // pointer-generator tail
  k_finps<<<3, 256, 0, stream>>>(psacc, puB);
  gemm_bt<3,2><<<5*391, 256, 0, stream>>>(ccatb, Woutb, nullptr, logitsb, b_out, 1536, 5, 391, VP, VV);
  k_softmax<<<TT*BB, 256, 0, stream>>>(logitsb, out, psacc);
  k_scatter<<<(TT*BB*SS + 255)/256, 256, 0, stream>>>(out, src, aeall, psacc);
}